// Round 9
// baseline (11689.170 us; speedup 1.0000x reference)
//
#include <hip/hip_runtime.h>
#include <hip/hip_bf16.h>

#define SEQ    256
#define BATCH  64
#define HID    1024
#define G4     4096
#define NWG    128
#define NTH    512

typedef __bf16 bf16x8 __attribute__((ext_vector_type(8)));
typedef float  f32x4  __attribute__((ext_vector_type(4)));
typedef unsigned short u16;

__device__ __forceinline__ u16 f2bf(float f) {
    unsigned int u = __float_as_uint(f);
    unsigned int r = (u + 0x7fffu + ((u >> 16) & 1u)) >> 16;  // RNE
    return (u16)r;
}
__device__ __forceinline__ float sigmoid_f(float x) {
    x = fminf(fmaxf(x, -30.f), 30.f);
    return 1.f / (1.f + __expf(-x));
}
__device__ __forceinline__ float tanh_f(float x) {
    x = fminf(fmaxf(x, -15.f), 15.f);
    float e2 = __expf(2.f * x);
    return (e2 - 1.f) / (e2 + 1.f);
}

// ---------------- prep: fp32->bf16 for x and Wx; zero flags ----------------
__global__ void prep_kernel(const float* __restrict__ x, u16* __restrict__ Xbf,
                            const float* __restrict__ Wx, u16* __restrict__ WxBf,
                            int* __restrict__ flags) {
    int idx = blockIdx.x * blockDim.x + threadIdx.x;
    if (idx < 1024)
        __hip_atomic_store(flags + idx, 0, __ATOMIC_RELAXED, __HIP_MEMORY_SCOPE_AGENT);
    int stride = gridDim.x * blockDim.x;
    int nx4 = SEQ * BATCH * HID / 4;
    const float4* in4 = (const float4*)x;
    ushort4* out4 = (ushort4*)Xbf;
    for (int i = idx; i < nx4; i += stride) {
        float4 v = in4[i];
        ushort4 o; o.x = f2bf(v.x); o.y = f2bf(v.y); o.z = f2bf(v.z); o.w = f2bf(v.w);
        out4[i] = o;
    }
    int nw4 = 2 * G4 * HID / 4;
    const float4* w4 = (const float4*)Wx;
    ushort4* wo4 = (ushort4*)WxBf;
    for (int i = idx; i < nw4; i += stride) {
        float4 v = w4[i];
        ushort4 o; o.x = f2bf(v.x); o.y = f2bf(v.y); o.z = f2bf(v.z); o.w = f2bf(v.w);
        wo4[i] = o;
    }
}

// ---- domain flag barrier: 64 WGs, each sc-stores own flag, wave0 polls 64 flags ----
__device__ __forceinline__ void bar_signal(int* df, int wl, int fid) {
    asm volatile("s_waitcnt vmcnt(0)" ::: "memory");  // sc-stores visible at L3
    __syncthreads();                                  // whole WG drained
    if (threadIdx.x == 0)
        __hip_atomic_store(df + wl, fid, __ATOMIC_RELAXED, __HIP_MEMORY_SCOPE_AGENT);
}
__device__ __forceinline__ void bar_poll(const int* df, int fid) {
    if (threadIdx.x < 64) {
        for (;;) {
            int v = __hip_atomic_load(df + (int)threadIdx.x, __ATOMIC_RELAXED,
                                      __HIP_MEMORY_SCOPE_AGENT);
            if (__all(v >= fid)) break;
            __builtin_amdgcn_s_sleep(1);
        }
    }
    __syncthreads();
}

#define SCLD(dst, base, OFFS) \
    asm volatile("global_load_dwordx4 %0, %1, off offset:" OFFS " sc0 sc1" \
                 : "=v"(dst) : "v"(base))
#define SCLD32(a, base) do { \
    SCLD(a[ 0],base,   "0"); SCLD(a[ 1],base,  "64"); SCLD(a[ 2],base, "128"); SCLD(a[ 3],base, "192"); \
    SCLD(a[ 4],base, "256"); SCLD(a[ 5],base, "320"); SCLD(a[ 6],base, "384"); SCLD(a[ 7],base, "448"); \
    SCLD(a[ 8],base, "512"); SCLD(a[ 9],base, "576"); SCLD(a[10],base, "640"); SCLD(a[11],base, "704"); \
    SCLD(a[12],base, "768"); SCLD(a[13],base, "832"); SCLD(a[14],base, "896"); SCLD(a[15],base, "960"); \
    SCLD(a[16],base,"1024"); SCLD(a[17],base,"1088"); SCLD(a[18],base,"1152"); SCLD(a[19],base,"1216"); \
    SCLD(a[20],base,"1280"); SCLD(a[21],base,"1344"); SCLD(a[22],base,"1408"); SCLD(a[23],base,"1472"); \
    SCLD(a[24],base,"1536"); SCLD(a[25],base,"1600"); SCLD(a[26],base,"1664"); SCLD(a[27],base,"1728"); \
    SCLD(a[28],base,"1792"); SCLD(a[29],base,"1856"); SCLD(a[30],base,"1920"); SCLD(a[31],base,"1984"); \
} while (0)

// 1-tile x-GEMM, plain (L2-cached) A and B
__device__ __forceinline__ f32x4 xgemm_plain(const u16* __restrict__ A, const u16* __restrict__ B) {
    f32x4 acc = {0.f,0.f,0.f,0.f};
    #pragma unroll
    for (int ks = 0; ks < 32; ++ks)
        acc = __builtin_amdgcn_mfma_f32_16x16x32_bf16(*(const bf16x8*)(A + ks * 32),
                                                      *(const bf16x8*)(B + ks * 32), acc, 0, 0, 0);
    return acc;
}

// 1-tile x-GEMM, sc-loads for A (Y0 cross-XCD), plain B
__device__ __forceinline__ f32x4 xgemm_sc(const u16* A, const u16* __restrict__ B) {
    bf16x8 xf[32];
    SCLD32(xf, A);
    asm volatile("s_waitcnt vmcnt(0)" ::: "memory");
    __builtin_amdgcn_sched_barrier(0);
    f32x4 acc = {0.f,0.f,0.f,0.f};
    #pragma unroll
    for (int ks = 0; ks < 32; ++ks)
        acc = __builtin_amdgcn_mfma_f32_16x16x32_bf16(xf[ks], *(const bf16x8*)(B + ks * 32), acc, 0, 0, 0);
    return acc;
}

// ---------------- persistent LSTM: 128 WGs x 512 threads, 2 independent domains ----------------
// WG (bh = bid>>6, wl = bid&63): batch rows [32bh,32bh+32), h-cols [16wl,16wl+16).
// 8 waves: wave w -> gate = w&3, bt = w>>2 (batch sub-tile) = one 16x16 D-tile.
// Cell phase: thread (b_l=tid>>4 in 0..31, c_l=tid&15).
__global__ void __launch_bounds__(NTH, 2) lstm_coop(
    const u16* __restrict__ Xbf,   // [SEQ][BATCH][HID] bf16
    u16* __restrict__ Y0bf,        // [SEQ][BATCH][HID] bf16 (L0 out, sc-accessed)
    const u16* __restrict__ WxBf,  // [2][4096][1024] bf16
    u16* __restrict__ hbuf,        // [2][BATCH][HID] bf16 (sc-accessed; halves disjoint)
    int* __restrict__ flags,       // [2][64]
    const float* __restrict__ h0,
    const float* __restrict__ c0,
    const float* __restrict__ Wh,  // [2][4096][1024] fp32
    const float* __restrict__ bx,
    const float* __restrict__ bh_, // bias h
    float* __restrict__ out)       // ys | hT | cT
{
    __shared__ u16   WhL[4][16384];     // per-gate Wh tile, fragment order
    __shared__ float gbuf[4 * 32 * 17]; // [gate][row 0..31][col 0..15], padded

    const int bid  = blockIdx.x;
    const int bhlf = bid >> 6;     // batch half
    const int wl   = bid & 63;
    const int hc0  = wl * 16;
    const int tid  = threadIdx.x;
    const int w    = tid >> 6;
    const int lane = tid & 63;
    const int gate = w & 3;
    const int bt   = w >> 2;       // 0/1
    const int fr   = lane & 15;
    const int fg   = lane >> 4;
    const int b_l  = tid >> 4;     // 0..31
    const int c_l  = tid & 15;

    int* dflags = flags + bhlf * 64;
    int fid = 0;

    const int row0 = bhlf * 32;    // this WG's batch-row base

    float* ys = out;
    float* hT = out + (size_t)SEQ * BATCH * HID;
    float* cT = hT + (size_t)2 * BATCH * HID;

    for (int layer = 0; layer < 2; ++layer) {
        // ---- stage Wh (own gate; wave bt stages its k-half), fragment order ----
        {
            size_t rowg = (size_t)layer * G4 + (size_t)gate * 1024 + hc0 + fr;
            const float* src = Wh + rowg * HID + fg * 8;
            u16* dst = &WhL[gate][lane * 8];
            #pragma unroll 4
            for (int kk = 0; kk < 16; ++kk) {
                int ks = bt * 16 + kk;
                float4 w0 = *(const float4*)(src + ks * 32);
                float4 w1 = *(const float4*)(src + ks * 32 + 4);
                ushort4 o0, o1;
                o0.x = f2bf(w0.x); o0.y = f2bf(w0.y); o0.z = f2bf(w0.z); o0.w = f2bf(w0.w);
                o1.x = f2bf(w1.x); o1.y = f2bf(w1.y); o1.z = f2bf(w1.z); o1.w = f2bf(w1.w);
                *(ushort4*)(dst + ks * 512)     = o0;
                *(ushort4*)(dst + ks * 512 + 4) = o1;
            }
        }
        const float bias_v = bx[layer * G4 + gate * 1024 + hc0 + fr]
                           + bh_[layer * G4 + gate * 1024 + hc0 + fr];

        // ---- init h (sc-stores, buffer 0) and per-thread c ----
        {
            float hv = h0[(size_t)layer * BATCH * HID + (size_t)(row0 + b_l) * HID + hc0 + c_l];
            u16* hdst = hbuf + (size_t)(row0 + b_l) * HID + hc0 + c_l;
            unsigned int hv32 = f2bf(hv);
            asm volatile("global_store_short %0, %1, off sc0 sc1" :: "v"(hdst), "v"(hv32) : "memory");
        }
        float c_reg = c0[(size_t)layer * BATCH * HID + (size_t)(row0 + b_l) * HID + hc0 + c_l];

        bar_signal(dflags, wl, ++fid);   // publishes h init (+ Y0 from prev layer, all sc)
        bar_poll(dflags, fid);

        const u16* Xsrc = (layer == 0) ? Xbf : Y0bf;
        const u16* WxB  = WxBf + ((size_t)layer * G4 + (size_t)gate * 1024 + hc0 + fr) * HID + fg * 8;
        const size_t xr = ((size_t)(row0 + bt * 16 + fr)) * HID + fg * 8;

        f32x4 accx = (layer == 0) ? xgemm_plain(Xsrc + xr, WxB)
                                  : xgemm_sc(Xsrc + xr, WxB);
        int cur = 0;
        float h_out = 0.f;

        for (int t = 0; t < SEQ; ++t) {
            // ---- h-GEMM: 32 sc-loads, one wait, 2 independent MFMA chains ----
            const u16* hb = hbuf + (size_t)cur * BATCH * HID
                          + (size_t)(row0 + bt * 16 + fr) * HID + fg * 8;
            bf16x8 hf[32];
            SCLD32(hf, hb);
            asm volatile("s_waitcnt vmcnt(0)" ::: "memory");
            __builtin_amdgcn_sched_barrier(0);
            f32x4 acc0 = accx;
            f32x4 acc1 = {0.f, 0.f, 0.f, 0.f};
            const u16* Bh = &WhL[gate][lane * 8];
            #pragma unroll
            for (int ks = 0; ks < 32; ks += 2) {
                acc0 = __builtin_amdgcn_mfma_f32_16x16x32_bf16(hf[ks],     *(const bf16x8*)(Bh + ks * 512),       acc0, 0, 0, 0);
                acc1 = __builtin_amdgcn_mfma_f32_16x16x32_bf16(hf[ks + 1], *(const bf16x8*)(Bh + (ks + 1) * 512), acc1, 0, 0, 0);
            }

            // ---- gates -> gbuf (cross-wave exchange) ----
            #pragma unroll
            for (int i = 0; i < 4; ++i)
                gbuf[(gate * 32 + bt * 16 + fg * 4 + i) * 17 + fr] = acc0[i] + acc1[i] + bias_v;
            __syncthreads();

            // ---- cell update ----
            float gi = gbuf[(0 * 32 + b_l) * 17 + c_l];
            float gf = gbuf[(1 * 32 + b_l) * 17 + c_l];
            float gg = gbuf[(2 * 32 + b_l) * 17 + c_l];
            float go = gbuf[(3 * 32 + b_l) * 17 + c_l];
            c_reg = sigmoid_f(gf) * c_reg + sigmoid_f(gi) * tanh_f(gg);
            h_out = sigmoid_f(go) * tanh_f(c_reg);

            unsigned int hbv = f2bf(h_out);
            {   // coherent write-through h store (L3-visible to all XCDs)
                u16* d0 = hbuf + (size_t)(cur ^ 1) * BATCH * HID
                        + (size_t)(row0 + b_l) * HID + hc0 + c_l;
                asm volatile("global_store_short %0, %1, off sc0 sc1" :: "v"(d0), "v"(hbv) : "memory");
            }
            if (layer == 0) {
                u16* y0 = Y0bf + ((size_t)t * BATCH + row0 + b_l) * HID + hc0 + c_l;
                asm volatile("global_store_short %0, %1, off sc0 sc1" :: "v"(y0), "v"(hbv) : "memory");
            } else {
                ys[((size_t)t * BATCH + row0 + b_l) * HID + hc0 + c_l] = h_out;
            }

            // ---- pipelined barrier: signal, prefetch next x, poll ----
            bar_signal(dflags, wl, ++fid);
            if (t < SEQ - 1) {
                const u16* A = Xsrc + (size_t)(t + 1) * BATCH * HID + xr;
                accx = (layer == 0) ? xgemm_plain(A, WxB) : xgemm_sc(A, WxB);
            }
            bar_poll(dflags, fid);
            cur ^= 1;
        }

        hT[(size_t)layer * BATCH * HID + (size_t)(row0 + b_l) * HID + hc0 + c_l] = h_out;
        cT[(size_t)layer * BATCH * HID + (size_t)(row0 + b_l) * HID + hc0 + c_l] = c_reg;
    }
}

extern "C" void kernel_launch(void* const* d_in, const int* in_sizes, int n_in,
                              void* d_out, int out_size, void* d_ws, size_t ws_size,
                              hipStream_t stream) {
    const float* x  = (const float*)d_in[0];
    const float* h0 = (const float*)d_in[1];
    const float* c0 = (const float*)d_in[2];
    const float* Wx = (const float*)d_in[3];
    const float* bx = (const float*)d_in[4];
    const float* Wh = (const float*)d_in[5];
    const float* bh = (const float*)d_in[6];
    float* out = (float*)d_out;

    u16* Xbf  = (u16*)d_ws;                                    // 16.78M elems
    u16* Y0bf = Xbf  + (size_t)SEQ * BATCH * HID;              // 16.78M elems
    u16* WxBf = Y0bf + (size_t)SEQ * BATCH * HID;              // 8.39M elems
    u16* hbuf = WxBf + (size_t)2 * G4 * HID;                   // 131072 elems
    int* flags = (int*)(hbuf + (size_t)2 * BATCH * HID);

    prep_kernel<<<dim3(1024), dim3(256), 0, stream>>>(x, Xbf, Wx, WxBf, flags);

    void* args[] = {(void*)&Xbf, (void*)&Y0bf, (void*)&WxBf, (void*)&hbuf, (void*)&flags,
                    (void*)&h0, (void*)&c0, (void*)&Wh, (void*)&bx, (void*)&bh, (void*)&out};
    hipError_t err = hipLaunchCooperativeKernel((void*)lstm_coop, dim3(NWG), dim3(NTH),
                                                args, 0, stream);
    if (err != hipSuccess) {
        (void)hipGetLastError();   // clear sticky error; 128 blocks are trivially co-resident
        lstm_coop<<<dim3(NWG), dim3(NTH), 0, stream>>>(Xbf, Y0bf, WxBf, hbuf, flags,
                                                       h0, c0, Wh, bx, bh, out);
    }
}

// Round 10
// 5006.212 us; speedup vs baseline: 2.3349x; 2.3349x over previous
//
#include <hip/hip_runtime.h>
#include <hip/hip_bf16.h>

#define SEQ    256
#define BATCH  64
#define HID    1024
#define G4     4096
#define NWG    256
#define LDK    1032   // padded LDS row stride (bf16 elems): 2064B rows, 2-way bank alias only

typedef __bf16 bf16x8 __attribute__((ext_vector_type(8)));
typedef float  f32x4  __attribute__((ext_vector_type(4)));
typedef unsigned short u16;

__device__ __forceinline__ u16 f2bf(float f) {
    unsigned int u = __float_as_uint(f);
    unsigned int r = (u + 0x7fffu + ((u >> 16) & 1u)) >> 16;  // RNE
    return (u16)r;
}

__device__ __forceinline__ float sigmoid_f(float x) {
    x = fminf(fmaxf(x, -30.f), 30.f);
    return 1.f / (1.f + __expf(-x));
}
__device__ __forceinline__ float tanh_f(float x) {
    x = fminf(fmaxf(x, -15.f), 15.f);
    float e2 = __expf(2.f * x);
    return (e2 - 1.f) / (e2 + 1.f);
}

// ---- split grid barrier: 2-level monotonic tree, relaxed agent atomics ----
// bar[64*g] g=0..7 : leaf counters; bar[768]: root; bar[832]: sense. Monotonic, no resets.
__device__ __forceinline__ void bar_arrive(int* bar, int target) {
    // drain outstanding vmem (h sc-store; prior outputs/prefetch long retired)
    asm volatile("s_waitcnt vmcnt(0)" ::: "memory");
    __syncthreads();   // all waves of this WG drained
    if (threadIdx.x == 0) {
        int* leaf  = bar + 64 * (blockIdx.x & 7);
        int* root  = bar + 768;
        int* sense = bar + 832;
        int p = __hip_atomic_fetch_add(leaf, 1, __ATOMIC_RELAXED, __HIP_MEMORY_SCOPE_AGENT);
        if (p == 32 * target - 1) {
            int q = __hip_atomic_fetch_add(root, 1, __ATOMIC_RELAXED, __HIP_MEMORY_SCOPE_AGENT);
            if (q == 8 * target - 1)
                __hip_atomic_store(sense, target, __ATOMIC_RELAXED, __HIP_MEMORY_SCOPE_AGENT);
        }
    }
}

__device__ __forceinline__ void bar_wait(int* bar, int target) {
    if (threadIdx.x == 0) {
        int* sense = bar + 832;
        while (__hip_atomic_load(sense, __ATOMIC_RELAXED, __HIP_MEMORY_SCOPE_AGENT) < target) { }
    }
    __syncthreads();
}

// heavy barrier: full L2 writeback/invalidate around it (layer boundaries only)
__device__ __forceinline__ void bar_heavy(int* bar, int target) {
    if (threadIdx.x == 0) __threadfence();   // release: wbl2 dirty Y0/hbuf-init lines
    bar_arrive(bar, target);
    bar_wait(bar, target);
    if (threadIdx.x == 0) __threadfence();   // acquire: inv stale L1/L2 copies
    __syncthreads();
}

// ---------------- fp32 -> bf16 conversion (x) + barrier-state init ----------------
__global__ void cvt_f32_bf16(const float* __restrict__ in, u16* __restrict__ out, int n4,
                             int* __restrict__ bar) {
    int idx = blockIdx.x * blockDim.x + threadIdx.x;
    if (idx < 1024) bar[idx] = 0;
    int stride = gridDim.x * blockDim.x;
    const float4* in4 = (const float4*)in;
    ushort4* out4 = (ushort4*)out;
    for (int i = idx; i < n4; i += stride) {
        float4 v = in4[i];
        ushort4 o;
        o.x = f2bf(v.x); o.y = f2bf(v.y); o.z = f2bf(v.z); o.w = f2bf(v.w);
        out4[i] = o;
    }
}

// x-GEMM for one step: A from global (L2-cached), B from LDS. 32 MFMAs.
__device__ __forceinline__ f32x4 xgemm(const u16* __restrict__ A0, const u16* B0) {
    f32x4 acc = {0.f, 0.f, 0.f, 0.f};
    #pragma unroll 8
    for (int ks = 0; ks < 32; ++ks) {
        bf16x8 a = *(const bf16x8*)(A0 + ks * 32);
        bf16x8 b = *(const bf16x8*)(B0 + ks * 32);
        acc = __builtin_amdgcn_mfma_f32_16x16x32_bf16(a, b, acc, 0, 0, 0);
    }
    return acc;
}

// issue one coherent (L2-bypassing) 16B h-frag load at byte offset OFFS
#define LDH(k, OFFS) \
    asm volatile("global_load_dwordx4 %0, %1, off offset:" OFFS " sc0 sc1" \
                 : "=v"(hf[k]) : "v"(A1))

// ---------------- persistent cooperative LSTM ----------------
// WG w owns h-columns [4w, 4w+4). Local gate row j = gate*4 + col (0..15).
// Wave v handles batch rows [16v, 16v+16).
__global__ void __launch_bounds__(256, 1) lstm_coop(
    const u16* Xbf,               // [SEQ][BATCH][HID] bf16
    u16* Y0bf,                    // [SEQ][BATCH][HID] bf16 (layer-0 outputs)
    u16* __restrict__ hbuf,       // [2][BATCH][HID] bf16 (double-buffered h)
    int* __restrict__ bar,        // barrier state
    const float* __restrict__ h0,
    const float* __restrict__ c0,
    const float* __restrict__ Wx, // [2][4096][1024]
    const float* __restrict__ bx,
    const float* __restrict__ Wh, // [2][4096][1024]
    const float* __restrict__ bh,
    float* __restrict__ out)      // ys | hT | cT
{
    __shared__ u16   WxL[16 * LDK];
    __shared__ u16   WhL[16 * LDK];
    __shared__ float biasL[16];
    __shared__ float gbuf[4][16][17];

    const int wg   = blockIdx.x;
    const int hc0  = wg * 4;
    const int tid  = threadIdx.x;
    const int wv   = tid >> 6;
    const int lane = tid & 63;
    const int fr   = lane & 15;
    const int fg   = lane >> 4;
    const int bl   = lane >> 2;
    const int col  = lane & 3;
    const int b_cell = wv * 16 + bl;

    int bar_id = 0;

    float* ys = out;
    float* hT = out + (size_t)SEQ * BATCH * HID;
    float* cT = hT + (size_t)2 * BATCH * HID;

    for (int layer = 0; layer < 2; ++layer) {
        for (int j = 0; j < 16; ++j) {
            int gate = j >> 2, jc = j & 3;
            size_t row = (size_t)layer * G4 + (size_t)gate * HID + hc0 + jc;
            const float4* sx = (const float4*)(Wx + row * HID);
            const float4* sh = (const float4*)(Wh + row * HID);
            float4 vx = sx[tid];
            float4 vh = sh[tid];
            ushort4 ox, oh;
            ox.x = f2bf(vx.x); ox.y = f2bf(vx.y); ox.z = f2bf(vx.z); ox.w = f2bf(vx.w);
            oh.x = f2bf(vh.x); oh.y = f2bf(vh.y); oh.z = f2bf(vh.z); oh.w = f2bf(vh.w);
            *(ushort4*)&WxL[j * LDK + tid * 4] = ox;
            *(ushort4*)&WhL[j * LDK + tid * 4] = oh;
        }
        if (tid < 16) {
            int gate = tid >> 2, jc = tid & 3;
            int row = layer * G4 + gate * HID + hc0 + jc;
            biasL[tid] = bx[row] + bh[row];
        }
        {
            int b = tid >> 2, cc = tid & 3;
            float hv = h0[(size_t)layer * BATCH * HID + (size_t)b * HID + hc0 + cc];
            hbuf[(size_t)b * HID + hc0 + cc] = f2bf(hv);   // buffer 0 (published by heavy bar)
        }
        float c_reg = c0[(size_t)layer * BATCH * HID + (size_t)b_cell * HID + hc0 + col];
        bar_heavy(bar, ++bar_id);   // publish hbuf init (+ Y0 from prev layer)

        const u16* Xsrc = (layer == 0) ? Xbf : Y0bf;
        const u16* B0 = &WxL[fr * LDK + fg * 8];
        const u16* B1 = &WhL[fr * LDK + fg * 8];
        const size_t arow = (size_t)(wv * 16 + fr) * HID + fg * 8;
        int cur = 0;
        float h_out = 0.f;

        // prologue: x-GEMM for t=0
        f32x4 accx = xgemm(Xsrc + arow, B0);

        for (int t = 0; t < SEQ; ++t) {
            // ---- h GEMM: issue all 32 coherent loads, one wait, 4 independent chains ----
            const u16* A1 = hbuf + (size_t)cur * BATCH * HID + arow;
            bf16x8 hf[32];
            LDH( 0,    "0"); LDH( 1,   "64"); LDH( 2,  "128"); LDH( 3,  "192");
            LDH( 4,  "256"); LDH( 5,  "320"); LDH( 6,  "384"); LDH( 7,  "448");
            LDH( 8,  "512"); LDH( 9,  "576"); LDH(10,  "640"); LDH(11,  "704");
            LDH(12,  "768"); LDH(13,  "832"); LDH(14,  "896"); LDH(15,  "960");
            LDH(16, "1024"); LDH(17, "1088"); LDH(18, "1152"); LDH(19, "1216");
            LDH(20, "1280"); LDH(21, "1344"); LDH(22, "1408"); LDH(23, "1472");
            LDH(24, "1536"); LDH(25, "1600"); LDH(26, "1664"); LDH(27, "1728");
            LDH(28, "1792"); LDH(29, "1856"); LDH(30, "1920"); LDH(31, "1984");
            asm volatile("s_waitcnt vmcnt(0)" ::: "memory");
            __builtin_amdgcn_sched_barrier(0);
            f32x4 acc0 = accx;
            f32x4 acc1 = {0.f, 0.f, 0.f, 0.f};
            f32x4 acc2 = {0.f, 0.f, 0.f, 0.f};
            f32x4 acc3 = {0.f, 0.f, 0.f, 0.f};
            #pragma unroll
            for (int ks = 0; ks < 32; ks += 4) {
                acc0 = __builtin_amdgcn_mfma_f32_16x16x32_bf16(hf[ks],     *(const bf16x8*)(B1 + ks * 32),       acc0, 0, 0, 0);
                acc1 = __builtin_amdgcn_mfma_f32_16x16x32_bf16(hf[ks + 1], *(const bf16x8*)(B1 + (ks + 1) * 32), acc1, 0, 0, 0);
                acc2 = __builtin_amdgcn_mfma_f32_16x16x32_bf16(hf[ks + 2], *(const bf16x8*)(B1 + (ks + 2) * 32), acc2, 0, 0, 0);
                acc3 = __builtin_amdgcn_mfma_f32_16x16x32_bf16(hf[ks + 3], *(const bf16x8*)(B1 + (ks + 3) * 32), acc3, 0, 0, 0);
            }

            float bias = biasL[fr];
            gbuf[wv][fg * 4 + 0][fr] = acc0[0] + acc1[0] + acc2[0] + acc3[0] + bias;
            gbuf[wv][fg * 4 + 1][fr] = acc0[1] + acc1[1] + acc2[1] + acc3[1] + bias;
            gbuf[wv][fg * 4 + 2][fr] = acc0[2] + acc1[2] + acc2[2] + acc3[2] + bias;
            gbuf[wv][fg * 4 + 3][fr] = acc0[3] + acc1[3] + acc2[3] + acc3[3] + bias;
            float gi = gbuf[wv][bl][0 + col];
            float gf = gbuf[wv][bl][4 + col];
            float gg = gbuf[wv][bl][8 + col];
            float go = gbuf[wv][bl][12 + col];

            c_reg = sigmoid_f(gf) * c_reg + sigmoid_f(gi) * tanh_f(gg);
            h_out = sigmoid_f(go) * tanh_f(c_reg);

            u16 hb = f2bf(h_out);
            {   // coherent write-through h store (visible at L3 to all XCDs)
                u16* hdst = hbuf + (size_t)(cur ^ 1) * BATCH * HID + (size_t)b_cell * HID + hc0 + col;
                unsigned int hv32 = hb;
                asm volatile("global_store_short %0, %1, off sc0 sc1"
                             :: "v"(hdst), "v"(hv32) : "memory");
            }

            // ---- arrive first (drains only the h store), then outputs + x-prefetch ----
            int tgt = ++bar_id;
            bar_arrive(bar, tgt);
            if (layer == 0) {
                Y0bf[(size_t)t * BATCH * HID + (size_t)b_cell * HID + hc0 + col] = hb;
            } else {
                ys[(size_t)t * BATCH * HID + (size_t)b_cell * HID + hc0 + col] = h_out;
            }
            int tn = (t + 1) & 255;
            f32x4 acc2n = xgemm(Xsrc + (size_t)tn * BATCH * HID + arow, B0);
            bar_wait(bar, tgt);
            accx = acc2n;
            cur ^= 1;
        }

        hT[(size_t)layer * BATCH * HID + (size_t)b_cell * HID + hc0 + col] = h_out;
        cT[(size_t)layer * BATCH * HID + (size_t)b_cell * HID + hc0 + col] = c_reg;

        bar_heavy(bar, ++bar_id);   // publish Y0 before next layer reads it
    }
}

extern "C" void kernel_launch(void* const* d_in, const int* in_sizes, int n_in,
                              void* d_out, int out_size, void* d_ws, size_t ws_size,
                              hipStream_t stream) {
    const float* x  = (const float*)d_in[0];
    const float* h0 = (const float*)d_in[1];
    const float* c0 = (const float*)d_in[2];
    const float* Wx = (const float*)d_in[3];
    const float* bx = (const float*)d_in[4];
    const float* Wh = (const float*)d_in[5];
    const float* bh = (const float*)d_in[6];
    float* out = (float*)d_out;

    u16* Xbf  = (u16*)d_ws;
    u16* Y0bf = Xbf + (size_t)SEQ * BATCH * HID;
    u16* hbuf = Y0bf + (size_t)SEQ * BATCH * HID;
    int* bar  = (int*)(hbuf + (size_t)2 * BATCH * HID);

    int n4 = (SEQ * BATCH * HID) / 4;
    cvt_f32_bf16<<<dim3(1024), dim3(256), 0, stream>>>(x, Xbf, n4, bar);

    void* args[] = {(void*)&Xbf, (void*)&Y0bf, (void*)&hbuf, (void*)&bar,
                    (void*)&h0, (void*)&c0, (void*)&Wx, (void*)&bx,
                    (void*)&Wh, (void*)&bh, (void*)&out};
    hipLaunchCooperativeKernel((void*)lstm_coop, dim3(NWG), dim3(256), args, 0, stream);
}